// Round 3
// baseline (344.211 us; speedup 1.0000x reference)
//
#include <hip/hip_runtime.h>

// Problem constants
#define QDIM   45184      // 64*64*9 + 64 + 2*64*64 + 64
#define CBOFF  36864      // cnn_b  [64]
#define PWOFF  36928      // proj_w [o][c] (64 x 128)
#define PBOFF  45120      // proj_b [64]
#define NPIX   256        // 16*16

// ws layout (floats): [0..8] alpha softmax (3 modules x 3),
//                     [16..27] tau0 softmax (3 x 4, zero padded),
//                     [32..43] tau1 softmax (3 x 4, zero padded)

__global__ void init_kernel(const float* __restrict__ img,
                            const float* __restrict__ alpha,
                            const float* __restrict__ tau0,
                            const float* __restrict__ tau1,
                            float* __restrict__ out,
                            float* __restrict__ sm)
{
    int t = blockIdx.x * blockDim.x + threadIdx.x;

    if (blockIdx.x == 0 && threadIdx.x == 0) {
        for (int i = 0; i < 3; ++i) {
            float v0 = alpha[i*3+0], v1 = alpha[i*3+1], v2 = alpha[i*3+2];
            float mx = fmaxf(fmaxf(v0, v1), v2);
            float e0 = expf(v0-mx), e1 = expf(v1-mx), e2 = expf(v2-mx);
            float s = e0+e1+e2;
            sm[i*3+0] = e0/s; sm[i*3+1] = e1/s; sm[i*3+2] = e2/s;
            int n = i + 2;
            {
                float mv = -1e30f;
                for (int m = 0; m < n; ++m) mv = fmaxf(mv, tau0[i*4+m]);
                float e[4]; float ss = 0.f;
                for (int m = 0; m < n; ++m) { e[m] = expf(tau0[i*4+m]-mv); ss += e[m]; }
                for (int m = 0; m < 4; ++m) sm[16+i*4+m] = (m < n) ? e[m]/ss : 0.f;
            }
            {
                float mv = -1e30f;
                for (int m = 0; m < n; ++m) mv = fmaxf(mv, tau1[i*4+m]);
                float e[4]; float ss = 0.f;
                for (int m = 0; m < n; ++m) { e[m] = expf(tau1[i*4+m]-mv); ss += e[m]; }
                for (int m = 0; m < 4; ++m) sm[32+i*4+m] = (m < n) ? e[m]/ss : 0.f;
            }
        }
    }

    // zero sentinel slot (m=0) and copy img into slot m=1, float4-wide
    const int nf4 = 128*64*256/4;        // 524288
    if (t < nf4) {
        const int per_sample = 64*256/4; // 4096 float4 per map
        int b = t / per_sample;
        int r = t - b*per_sample;
        const float4* im4 = (const float4*)img;
        float4* o4 = (float4*)out;
        float4 z; z.x = z.y = z.z = z.w = 0.f;
        size_t base = (size_t)b * 5 * per_sample;
        o4[base + r]              = z;           // sentinel
        o4[base + per_sample + r] = im4[t];      // img
    }
}

template<int MOD>
__global__ __launch_bounds__(512, 1)
void module_kernel(const float* __restrict__ question,
                   const float* __restrict__ img,
                   const float* __restrict__ sm,
                   float* __restrict__ out)
{
    const int b   = blockIdx.x >> 1;
    const int oh  = blockIdx.x & 1;     // output-channel half (32 ch each)
    const int tid = threadIdx.x;

    // projection output, padded +-32 floats so 3x aligned float4 window loads
    // (incl. clamped row -1 / 16 and q==0/q==3 over-reach) stay in-bounds.
    __shared__ __align__(16) float inp_pad[32 + 64*256 + 32];   // 64.25 KB
    __shared__ __align__(16) float wbuf[18432];                 // 72 KB
    __shared__ float pb_s[64];
    __shared__ float cb_s[32];

    const float* q0 = question + (size_t)(b*3+0)*QDIM;
    const float* q1 = q0 + QDIM;
    const float* q2 = q0 + 2*QDIM;

    const float a0 = sm[MOD*3+0], a1 = sm[MOD*3+1], a2 = sm[MOD*3+2];
    float t0[4], t1[4];
    #pragma unroll
    for (int m = 0; m < 4; ++m) { t0[m] = sm[16+MOD*4+m]; t1[m] = sm[32+MOD*4+m]; }

    // ---------- Phase A stage: combined proj weights [o][c] ----------
    #pragma unroll
    for (int k = 0; k < 16; ++k) {
        int idx = k*512 + tid;               // 0..8191
        int qo  = PWOFF + idx;
        wbuf[idx] = a0*q0[qo] + a1*q1[qo] + a2*q2[qo];
    }
    if (tid < 64) {
        int qo = PBOFF + tid;
        pb_s[tid] = a0*q0[qo] + a1*q1[qo] + a2*q2[qo];
    }
    __syncthreads();

    // ---------- Phase A compute: thread = (o-quarter of 16, pixel pair) ----------
    {
        const int oq  = tid >> 7;            // 0..3: which 16 output channels
        const int pp  = tid & 127;           // pixel pair
        const int px0 = pp * 2;

        float2 acc[16];
        #pragma unroll
        for (int o2 = 0; o2 < 16; ++o2) {
            float pb = pb_s[oq*16 + o2];
            acc[o2].x = pb; acc[o2].y = pb;
        }

        const float* imgb = img + (size_t)b*64*NPIX;
        const float* outb = out + (size_t)b*5*64*NPIX;

        for (int c4 = 0; c4 < 16; ++c4) {
            const int c = c4*4;
            float2 xv0[4], xv1[4];
            #pragma unroll
            for (int j = 0; j < 4; ++j) {
                float2 v = *(const float2*)&imgb[(c+j)*NPIX + px0];
                float2 s0, s1;
                s0.x = t0[1]*v.x; s0.y = t0[1]*v.y;
                s1.x = t1[1]*v.x; s1.y = t1[1]*v.y;
                if (MOD >= 1) {
                    float2 h = *(const float2*)&outb[(2*64 + c+j)*NPIX + px0];
                    s0.x += t0[2]*h.x; s0.y += t0[2]*h.y;
                    s1.x += t1[2]*h.x; s1.y += t1[2]*h.y;
                }
                if (MOD >= 2) {
                    float2 h = *(const float2*)&outb[(3*64 + c+j)*NPIX + px0];
                    s0.x += t0[3]*h.x; s0.y += t0[3]*h.y;
                    s1.x += t1[3]*h.x; s1.y += t1[3]*h.y;
                }
                xv0[j] = s0; xv1[j] = s1;
            }
            #pragma unroll
            for (int o2 = 0; o2 < 16; ++o2) {
                const int o = oq*16 + o2;
                const float4 w0 = *(const float4*)&wbuf[o*128 + c];
                const float4 w1 = *(const float4*)&wbuf[o*128 + 64 + c];
                acc[o2].x += w0.x*xv0[0].x + w0.y*xv0[1].x + w0.z*xv0[2].x + w0.w*xv0[3].x
                           + w1.x*xv1[0].x + w1.y*xv1[1].x + w1.z*xv1[2].x + w1.w*xv1[3].x;
                acc[o2].y += w0.x*xv0[0].y + w0.y*xv0[1].y + w0.z*xv0[2].y + w0.w*xv0[3].y
                           + w1.x*xv1[0].y + w1.y*xv1[1].y + w1.z*xv1[2].y + w1.w*xv1[3].y;
            }
        }
        #pragma unroll
        for (int o2 = 0; o2 < 16; ++o2) {
            const int o = oq*16 + o2;
            *(float2*)&inp_pad[32 + o*NPIX + px0] = acc[o2];
        }
    }
    __syncthreads();   // all reads of wbuf (proj) + writes of inp_pad done

    // ---------- Phase B stage: this half's conv weights [32][64][9] ----------
    const int obase = oh*32;
    #pragma unroll
    for (int k = 0; k < 36; ++k) {
        int idx = k*512 + tid;               // 0..18431
        int qo  = obase*576 + idx;           // contiguous slice of cnn_w
        wbuf[idx] = a0*q0[qo] + a1*q1[qo] + a2*q2[qo];
    }
    if (tid < 32) {
        int qo = CBOFF + obase + tid;
        cb_s[tid] = a0*q0[qo] + a1*q1[qo] + a2*q2[qo];
    }
    __syncthreads();

    // ---------- Phase B compute: thread = (o-group of 4, 4-px group) ----------
    // og = tid>>6 is wave-uniform => weight reads broadcast; neighborhood
    // reads are canonical 16B-stride ds_read_b128 within each 16-lane group.
    const int og  = tid >> 6;                // 0..7 (4 out-ch each)
    const int pg  = tid & 63;                // 4-px group
    const int row = pg >> 2;                 // 0..15
    const int q   = pg & 3;                  // which quarter-row
    const int x0  = q << 2;

    const bool qgt0 = (q > 0);
    const bool qlt3 = (q < 3);

    float acc[4][4];
    #pragma unroll
    for (int ol = 0; ol < 4; ++ol) {
        float cb = cb_s[og*4 + ol];
        #pragma unroll
        for (int p = 0; p < 4; ++p) acc[ol][p] = cb;
    }

    for (int c = 0; c < 64; ++c) {
        // window floats x0-1 .. x0+4 for rows row-1..row+1, zero-padded
        float win[3][6];
        #pragma unroll
        for (int dy = 0; dy < 3; ++dy) {
            const int yy  = row + dy - 1;
            const bool yok = ((unsigned)yy < 16u);
            const float4* base =
                (const float4*)&inp_pad[32 + c*NPIX + yy*16 + x0 - 4];
            float4 A  = base[0];   // floats x0-4 .. x0-1
            float4 Bv = base[1];   // floats x0   .. x0+3
            float4 C  = base[2];   // floats x0+4 .. x0+7
            win[dy][0] = (yok && qgt0) ? A.w  : 0.f;
            win[dy][1] = yok ? Bv.x : 0.f;
            win[dy][2] = yok ? Bv.y : 0.f;
            win[dy][3] = yok ? Bv.z : 0.f;
            win[dy][4] = yok ? Bv.w : 0.f;
            win[dy][5] = (yok && qlt3) ? C.x : 0.f;
        }
        #pragma unroll
        for (int ol = 0; ol < 4; ++ol) {
            const float* wt = &wbuf[(og*4 + ol)*576 + c*9];
            float w[9];
            #pragma unroll
            for (int k = 0; k < 9; ++k) w[k] = wt[k];
            #pragma unroll
            for (int p = 0; p < 4; ++p) {
                acc[ol][p] += w[0]*win[0][p] + w[1]*win[0][p+1] + w[2]*win[0][p+2]
                            + w[3]*win[1][p] + w[4]*win[1][p+1] + w[5]*win[1][p+2]
                            + w[6]*win[2][p] + w[7]*win[2][p+1] + w[8]*win[2][p+2];
            }
        }
    }

    float* ob = out + ((size_t)(b*5 + 2 + MOD)*64 + obase + og*4)*NPIX + row*16 + x0;
    #pragma unroll
    for (int ol = 0; ol < 4; ++ol) {
        float4 v;
        v.x = fmaxf(acc[ol][0], 0.f);
        v.y = fmaxf(acc[ol][1], 0.f);
        v.z = fmaxf(acc[ol][2], 0.f);
        v.w = fmaxf(acc[ol][3], 0.f);
        *(float4*)&ob[ol*NPIX] = v;
    }
}

extern "C" void kernel_launch(void* const* d_in, const int* in_sizes, int n_in,
                              void* d_out, int out_size, void* d_ws, size_t ws_size,
                              hipStream_t stream)
{
    const float* question = (const float*)d_in[0];  // (128, 3, 45184)
    const float* img      = (const float*)d_in[1];  // (128, 64, 16, 16)
    const float* alpha    = (const float*)d_in[2];  // (3, 3)
    const float* tau0     = (const float*)d_in[3];  // (3, 4)
    const float* tau1     = (const float*)d_in[4];  // (3, 4)
    float* out = (float*)d_out;                     // (128, 1, 5, 64, 16, 16)
    float* sm  = (float*)d_ws;                      // 48 floats used

    init_kernel<<<2048, 256, 0, stream>>>(img, alpha, tau0, tau1, out, sm);

    module_kernel<0><<<256, 512, 0, stream>>>(question, img, sm, out);
    module_kernel<1><<<256, 512, 0, stream>>>(question, img, sm, out);
    module_kernel<2><<<256, 512, 0, stream>>>(question, img, sm, out);
}

// Round 5
// 321.406 us; speedup vs baseline: 1.0710x; 1.0710x over previous
//
#include <hip/hip_runtime.h>

// Problem constants
#define QDIM   45184      // 64*64*9 + 64 + 2*64*64 + 64
#define CBOFF  36864      // cnn_b  [64]
#define PWOFF  36928      // proj_w [o][c] (64 x 128)
#define PBOFF  45120      // proj_b [64]
#define NPIX   256        // 16*16

// LDS float-index XOR swizzle: spreads rows (32-float strides) across banks.
// Key bits (fa>>5)&7 are invariant under +256*k, so swizzled bases can be
// precomputed and incremented by channel stride. Bits 0-1 untouched ->
// aligned float2/float4 groups stay contiguous.
__device__ __forceinline__ int swz(int fa) { return fa ^ (((fa >> 5) & 7) << 2); }

__global__ void init_kernel(const float* __restrict__ img,
                            const float* __restrict__ alpha,
                            const float* __restrict__ tau0,
                            const float* __restrict__ tau1,
                            float* __restrict__ out,
                            float* __restrict__ sm)
{
    int t = blockIdx.x * blockDim.x + threadIdx.x;

    if (blockIdx.x == 0 && threadIdx.x == 0) {
        for (int i = 0; i < 3; ++i) {
            float v0 = alpha[i*3+0], v1 = alpha[i*3+1], v2 = alpha[i*3+2];
            float mx = fmaxf(fmaxf(v0, v1), v2);
            float e0 = expf(v0-mx), e1 = expf(v1-mx), e2 = expf(v2-mx);
            float s = e0+e1+e2;
            sm[i*3+0] = e0/s; sm[i*3+1] = e1/s; sm[i*3+2] = e2/s;
            int n = i + 2;
            {
                float mv = -1e30f;
                for (int m = 0; m < n; ++m) mv = fmaxf(mv, tau0[i*4+m]);
                float e[4]; float ss = 0.f;
                for (int m = 0; m < n; ++m) { e[m] = expf(tau0[i*4+m]-mv); ss += e[m]; }
                for (int m = 0; m < 4; ++m) sm[16+i*4+m] = (m < n) ? e[m]/ss : 0.f;
            }
            {
                float mv = -1e30f;
                for (int m = 0; m < n; ++m) mv = fmaxf(mv, tau1[i*4+m]);
                float e[4]; float ss = 0.f;
                for (int m = 0; m < n; ++m) { e[m] = expf(tau1[i*4+m]-mv); ss += e[m]; }
                for (int m = 0; m < 4; ++m) sm[32+i*4+m] = (m < n) ? e[m]/ss : 0.f;
            }
        }
    }

    // zero sentinel slot (m=0) and copy img into slot m=1, float4-wide
    const int nf4 = 128*64*256/4;        // 524288
    if (t < nf4) {
        const int per_sample = 64*256/4; // 4096 float4 per map
        int b = t / per_sample;
        int r = t - b*per_sample;
        const float4* im4 = (const float4*)img;
        float4* o4 = (float4*)out;
        float4 z; z.x = z.y = z.z = z.w = 0.f;
        size_t base = (size_t)b * 5 * per_sample;
        o4[base + r]              = z;           // sentinel
        o4[base + per_sample + r] = im4[t];      // img
    }
}

template<int MOD>
__global__ __launch_bounds__(512, 1)
void module_kernel(const float* __restrict__ question,
                   const float* __restrict__ img,
                   const float* __restrict__ sm,
                   float* __restrict__ out)
{
    const int b   = blockIdx.x >> 1;
    const int oh  = blockIdx.x & 1;     // output-channel half (32 ch each)
    const int tid = threadIdx.x;

    // projection output (swizzled), padded so window loads stay in-bounds
    __shared__ __align__(16) float  inp_pad[16448];       // 64.3 KB
    __shared__ __align__(16) float4 wA[2048];             // conv w0..3  (32 KB); phase A: proj weights
    __shared__ __align__(16) float4 wB[2048];             // conv w4..7  (32 KB)
    __shared__ float wC[2048];                            // conv w8     (8 KB)
    __shared__ float pb_s[64];
    __shared__ float cb_s[32];

    const float* q0 = question + (size_t)(b*3+0)*QDIM;
    const float* q1 = q0 + QDIM;
    const float* q2 = q0 + 2*QDIM;
    const float4* q04 = (const float4*)q0;
    const float4* q14 = (const float4*)q1;
    const float4* q24 = (const float4*)q2;

    const float a0 = sm[MOD*3+0], a1 = sm[MOD*3+1], a2 = sm[MOD*3+2];
    float t0[4], t1[4];
    #pragma unroll
    for (int m = 0; m < 4; ++m) { t0[m] = sm[16+MOD*4+m]; t1[m] = sm[32+MOD*4+m]; }

    // ---------- Phase A stage: combined proj weights [o][c], float4-wide ----------
    {
        float4* proj4 = wA;
        #pragma unroll
        for (int k = 0; k < 4; ++k) {
            int idx = k*512 + tid;               // 0..2047 float4s
            float4 v0 = q04[PWOFF/4 + idx];
            float4 v1 = q14[PWOFF/4 + idx];
            float4 v2 = q24[PWOFF/4 + idx];
            float4 w;
            w.x = a0*v0.x + a1*v1.x + a2*v2.x;
            w.y = a0*v0.y + a1*v1.y + a2*v2.y;
            w.z = a0*v0.z + a1*v1.z + a2*v2.z;
            w.w = a0*v0.w + a1*v1.w + a2*v2.w;
            proj4[idx] = w;
        }
        if (tid < 16) {
            float4 v0 = q04[PBOFF/4 + tid];
            float4 v1 = q14[PBOFF/4 + tid];
            float4 v2 = q24[PBOFF/4 + tid];
            float4 w;
            w.x = a0*v0.x + a1*v1.x + a2*v2.x;
            w.y = a0*v0.y + a1*v1.y + a2*v2.y;
            w.z = a0*v0.z + a1*v1.z + a2*v2.z;
            w.w = a0*v0.w + a1*v1.w + a2*v2.w;
            ((float4*)pb_s)[tid] = w;
        }
    }
    __syncthreads();

    // ---------- Phase A compute: thread = (o-quarter of 16, pixel pair) ----------
    {
        const int oq  = tid >> 7;            // 0..3: which 16 output channels
        const int pp  = tid & 127;           // pixel pair
        const int px0 = pp * 2;
        const float4* proj4 = wA;

        float2 acc[16];
        #pragma unroll
        for (int o2 = 0; o2 < 16; ++o2) {
            float pb = pb_s[oq*16 + o2];
            acc[o2].x = pb; acc[o2].y = pb;
        }

        const float* imgb = img + (size_t)b*64*NPIX;
        const float* outb = out + (size_t)b*5*64*NPIX;

        for (int c4 = 0; c4 < 16; ++c4) {
            const int c = c4*4;
            float2 xv0[4], xv1[4];
            #pragma unroll
            for (int j = 0; j < 4; ++j) {
                float2 v = *(const float2*)&imgb[(c+j)*NPIX + px0];
                float2 s0, s1;
                s0.x = t0[1]*v.x; s0.y = t0[1]*v.y;
                s1.x = t1[1]*v.x; s1.y = t1[1]*v.y;
                if (MOD >= 1) {
                    float2 h = *(const float2*)&outb[(2*64 + c+j)*NPIX + px0];
                    s0.x += t0[2]*h.x; s0.y += t0[2]*h.y;
                    s1.x += t1[2]*h.x; s1.y += t1[2]*h.y;
                }
                if (MOD >= 2) {
                    float2 h = *(const float2*)&outb[(3*64 + c+j)*NPIX + px0];
                    s0.x += t0[3]*h.x; s0.y += t0[3]*h.y;
                    s1.x += t1[3]*h.x; s1.y += t1[3]*h.y;
                }
                xv0[j] = s0; xv1[j] = s1;
            }
            #pragma unroll
            for (int o2 = 0; o2 < 16; ++o2) {
                const int o = oq*16 + o2;
                const float4 w0 = proj4[o*32 + c4];
                const float4 w1 = proj4[o*32 + 16 + c4];
                acc[o2].x += w0.x*xv0[0].x + w0.y*xv0[1].x + w0.z*xv0[2].x + w0.w*xv0[3].x
                           + w1.x*xv1[0].x + w1.y*xv1[1].x + w1.z*xv1[2].x + w1.w*xv1[3].x;
                acc[o2].y += w0.x*xv0[0].y + w0.y*xv0[1].y + w0.z*xv0[2].y + w0.w*xv0[3].y
                           + w1.x*xv1[0].y + w1.y*xv1[1].y + w1.z*xv1[2].y + w1.w*xv1[3].y;
            }
        }
        const int wbase = swz(32 + px0);     // swz(x + o*256) == swz(x) + o*256
        #pragma unroll
        for (int o2 = 0; o2 < 16; ++o2) {
            const int o = oq*16 + o2;
            *(float2*)&inp_pad[wbase + o*NPIX] = acc[o2];
        }
    }
    __syncthreads();   // proj reads + inp writes done

    // ---------- Phase B stage: this half's conv weights, float4 + scatter ----------
    const int obase = oh*32;
    {
        float* pA = (float*)wA;
        float* pB = (float*)wB;
        const int src4 = (obase*576) >> 2;       // float4 offset of this half's slice
        #pragma unroll
        for (int i = 0; i < 9; ++i) {
            unsigned idx4 = i*512 + tid;         // 0..4607
            float4 v0 = q04[src4 + idx4];
            float4 v1 = q14[src4 + idx4];
            float4 v2 = q24[src4 + idx4];
            float cmb[4];
            cmb[0] = a0*v0.x + a1*v1.x + a2*v2.x;
            cmb[1] = a0*v0.y + a1*v1.y + a2*v2.y;
            cmb[2] = a0*v0.z + a1*v1.z + a2*v2.z;
            cmb[3] = a0*v0.w + a1*v1.w + a2*v2.w;
            #pragma unroll
            for (int e = 0; e < 4; ++e) {
                unsigned g  = idx4*4u + e;       // 0..18431
                unsigned ch = g / 576u;
                unsigned r  = g - ch*576u;
                unsigned c  = r / 9u;
                unsigned k  = r - c*9u;
                float* dst = (k < 4u) ? &pA[ch*256u + c*4u + k]
                           : (k < 8u) ? &pB[ch*256u + c*4u + (k-4u)]
                                      : &wC[ch*64u + c];
                *dst = cmb[e];
            }
        }
        if (tid < 8) {
            float4 v0 = q04[CBOFF/4 + obase/4 + tid];
            float4 v1 = q14[CBOFF/4 + obase/4 + tid];
            float4 v2 = q24[CBOFF/4 + obase/4 + tid];
            float4 w;
            w.x = a0*v0.x + a1*v1.x + a2*v2.x;
            w.y = a0*v0.y + a1*v1.y + a2*v2.y;
            w.z = a0*v0.z + a1*v1.z + a2*v2.z;
            w.w = a0*v0.w + a1*v1.w + a2*v2.w;
            ((float4*)cb_s)[tid] = w;
        }
    }
    __syncthreads();

    // ---------- Phase B compute: thread = (o-group of 4, 4-px group) ----------
    const int og  = tid >> 6;                // 0..7 (4 out-ch each), wave-uniform
    const int pg  = tid & 63;                // 4-px group
    const int row = pg >> 2;                 // 0..15
    const int q   = pg & 3;                  // quarter-row
    const int x0  = q << 2;

    const bool qgt0 = (q > 0);
    const bool qlt3 = (q < 3);

    // precompute swizzled window bases (c=0); +256 per channel preserves swz
    int wbse[3][3];
    #pragma unroll
    for (int dy = 0; dy < 3; ++dy) {
        const int yy = row + dy - 1;
        const int lin = 32 + yy*16 + x0 - 4;     // min 12 (yy=-1,x0=0) -> in-bounds
        wbse[dy][0] = swz(lin);
        wbse[dy][1] = swz(lin + 4);
        wbse[dy][2] = swz(lin + 8);
    }

    float acc[4][4];
    #pragma unroll
    for (int ol = 0; ol < 4; ++ol) {
        float cb = cb_s[og*4 + ol];
        #pragma unroll
        for (int p = 0; p < 4; ++p) acc[ol][p] = cb;
    }

    for (int c = 0; c < 64; ++c) {
        float win[3][6];
        #pragma unroll
        for (int dy = 0; dy < 3; ++dy) {
            const int yy  = row + dy - 1;
            const bool yok = ((unsigned)yy < 16u);
            const int cb256 = c*NPIX;
            float4 A  = *(const float4*)&inp_pad[cb256 + wbse[dy][0]];
            float4 Bv = *(const float4*)&inp_pad[cb256 + wbse[dy][1]];
            float4 C  = *(const float4*)&inp_pad[cb256 + wbse[dy][2]];
            win[dy][0] = (yok && qgt0) ? A.w  : 0.f;
            win[dy][1] = yok ? Bv.x : 0.f;
            win[dy][2] = yok ? Bv.y : 0.f;
            win[dy][3] = yok ? Bv.z : 0.f;
            win[dy][4] = yok ? Bv.w : 0.f;
            win[dy][5] = (yok && qlt3) ? C.x : 0.f;
        }
        #pragma unroll
        for (int ol = 0; ol < 4; ++ol) {
            const int wi = (og*4 + ol)*64 + c;       // wave-uniform -> broadcast
            const float4 wa  = wA[wi];               // w0..w3
            const float4 wbv = wB[wi];               // w4..w7
            const float  wc8 = wC[wi];               // w8
            #pragma unroll
            for (int p = 0; p < 4; ++p) {
                acc[ol][p] += wa.x*win[0][p] + wa.y*win[0][p+1] + wa.z*win[0][p+2]
                            + wa.w*win[1][p] + wbv.x*win[1][p+1] + wbv.y*win[1][p+2]
                            + wbv.z*win[2][p] + wbv.w*win[2][p+1] + wc8*win[2][p+2];
            }
        }
    }

    float* ob = out + ((size_t)(b*5 + 2 + MOD)*64 + obase + og*4)*NPIX + row*16 + x0;
    #pragma unroll
    for (int ol = 0; ol < 4; ++ol) {
        float4 v;
        v.x = fmaxf(acc[ol][0], 0.f);
        v.y = fmaxf(acc[ol][1], 0.f);
        v.z = fmaxf(acc[ol][2], 0.f);
        v.w = fmaxf(acc[ol][3], 0.f);
        *(float4*)&ob[ol*NPIX] = v;
    }
}

extern "C" void kernel_launch(void* const* d_in, const int* in_sizes, int n_in,
                              void* d_out, int out_size, void* d_ws, size_t ws_size,
                              hipStream_t stream)
{
    const float* question = (const float*)d_in[0];  // (128, 3, 45184)
    const float* img      = (const float*)d_in[1];  // (128, 64, 16, 16)
    const float* alpha    = (const float*)d_in[2];  // (3, 3)
    const float* tau0     = (const float*)d_in[3];  // (3, 4)
    const float* tau1     = (const float*)d_in[4];  // (3, 4)
    float* out = (float*)d_out;                     // (128, 1, 5, 64, 16, 16)
    float* sm  = (float*)d_ws;                      // 48 floats used

    init_kernel<<<2048, 256, 0, stream>>>(img, alpha, tau0, tau1, out, sm);

    module_kernel<0><<<256, 512, 0, stream>>>(question, img, sm, out);
    module_kernel<1><<<256, 512, 0, stream>>>(question, img, sm, out);
    module_kernel<2><<<256, 512, 0, stream>>>(question, img, sm, out);
}